// Round 1
// baseline (883.178 us; speedup 1.0000x reference)
//
#include <hip/hip_runtime.h>

#define T_TOK 8192
#define DM    1024
#define DFF   4096
#define NE    8
#define SLOTS_MAX 17408
#define BM 128
#define BN 128
#define BK 32

typedef __attribute__((ext_vector_type(4))) float f32x4;
typedef __attribute__((ext_vector_type(8))) short bf16x8;

__device__ __forceinline__ unsigned short f2bf(float f) {
  unsigned int u = __float_as_uint(f);
  u = (u + 0x7FFFu + ((u >> 16) & 1u)) >> 16;
  return (unsigned short)u;
}

__device__ __forceinline__ void gld_lds16(const void* g, void* l) {
  __builtin_amdgcn_global_load_lds(
      (const __attribute__((address_space(1))) void*)g,
      (__attribute__((address_space(3))) void*)l, 16, 0, 0);
}

// ---------- weight transpose + fp32->bf16:  W [E][R][C] -> Wt [E][C][R] ----------
__global__ __launch_bounds__(256) void transpose_convert(
    const float* __restrict__ W, unsigned short* __restrict__ Wt, int R, int C)
{
  __shared__ float tile[32][33];
  int e = blockIdx.z;
  const float* We = W + (size_t)e * R * C;
  unsigned short* Wte = Wt + (size_t)e * R * C;
  int c0 = blockIdx.x * 32, r0 = blockIdx.y * 32;
  int tx = threadIdx.x & 31, ty = threadIdx.x >> 5;
#pragma unroll
  for (int i = 0; i < 4; ++i)
    tile[ty + i * 8][tx] = We[(size_t)(r0 + ty + i * 8) * C + c0 + tx];
  __syncthreads();
#pragma unroll
  for (int i = 0; i < 4; ++i)
    Wte[(size_t)(c0 + ty + i * 8) * R + r0 + tx] = f2bf(tile[tx][ty + i * 8]);
}

// ---------- router: wave per token ----------
__global__ __launch_bounds__(256) void router_kernel(
    const float* __restrict__ x, const float* __restrict__ Wg, const float* __restrict__ bg,
    int* __restrict__ topk_idx, float* __restrict__ topk_w,
    int* __restrict__ cnt_sh, float* __restrict__ P_sh)
{
  __shared__ float wgT[NE * DM];   // Wg transposed: [e][d], float4-readable
  for (int i = threadIdx.x; i < NE * DM; i += 256) {
    int d = i >> 3, e = i & 7;
    wgT[e * DM + d] = Wg[i];
  }
  __syncthreads();
  int w = threadIdx.x >> 6, lane = threadIdx.x & 63;
  int sh = blockIdx.x & 63;
  for (int it = 0; it < 4; ++it) {
    int t = (blockIdx.x * 4 + w) * 4 + it;
    float p[NE];
#pragma unroll
    for (int e = 0; e < NE; ++e) p[e] = 0.f;
#pragma unroll
    for (int ps = 0; ps < 4; ++ps) {
      int d0 = ps * 256 + lane * 4;
      float4 xv = *(const float4*)(x + (size_t)t * DM + d0);
#pragma unroll
      for (int e = 0; e < NE; ++e) {
        float4 wv = *(const float4*)(wgT + e * DM + d0);
        p[e] += xv.x * wv.x + xv.y * wv.y + xv.z * wv.z + xv.w * wv.w;
      }
    }
#pragma unroll
    for (int e = 0; e < NE; ++e) {
#pragma unroll
      for (int o = 1; o < 64; o <<= 1) p[e] += __shfl_xor(p[e], o);
      p[e] += bg[e];
    }
    float mx = p[0];
#pragma unroll
    for (int e = 1; e < NE; ++e) mx = fmaxf(mx, p[e]);
    float se = 0.f;
#pragma unroll
    for (int e = 0; e < NE; ++e) { p[e] = expf(p[e] - mx); se += p[e]; }
    float inv = 1.f / se;
#pragma unroll
    for (int e = 0; e < NE; ++e) p[e] *= inv;
    // top-2, ties -> lower index (matches lax.top_k)
    int e0 = 0; float v0 = p[0];
#pragma unroll
    for (int e = 1; e < NE; ++e) if (p[e] > v0) { v0 = p[e]; e0 = e; }
    int e1 = -1; float v1 = -1.f;
#pragma unroll
    for (int e = 0; e < NE; ++e) if (e != e0 && p[e] > v1) { v1 = p[e]; e1 = e; }
    if (lane == 0) {
      topk_idx[t * 2] = e0; topk_idx[t * 2 + 1] = e1;
      topk_w[t * 2] = v0;  topk_w[t * 2 + 1] = v1;
      atomicAdd(&cnt_sh[sh * 8 + e0], 1);
      atomicAdd(&cnt_sh[sh * 8 + e1], 1);
#pragma unroll
      for (int e = 0; e < NE; ++e) atomicAdd(&P_sh[sh * 8 + e], p[e]);
    }
  }
}

// ---------- reduce shadow counts, build 128-aligned per-expert offsets ----------
__global__ void offsets_kernel(const int* __restrict__ cnt_sh,
                               int* __restrict__ count, int* __restrict__ expOff)
{
  int e = threadIdx.x;
  if (e < NE) {
    int c = 0;
    for (int i = 0; i < 64; ++i) c += cnt_sh[i * 8 + e];
    count[e] = c;
  }
  __syncthreads();
  if (threadIdx.x == 0) {
    int o = 0;
    for (int q = 0; q < NE; ++q) {
      expOff[q] = o;
      o += ((count[q] + 127) >> 7) << 7;
    }
    expOff[NE] = o;
  }
}

// ---------- gather: wave per (token,k) slot; x row fp32 -> bf16 ----------
__global__ __launch_bounds__(256) void gather_kernel(
    const float* __restrict__ x, const int* __restrict__ topk_idx,
    const float* __restrict__ topk_w, const int* __restrict__ expOff,
    int* __restrict__ pos, int* __restrict__ slot_tok, float* __restrict__ slot_w,
    unsigned short* __restrict__ Abuf)
{
  int w = threadIdx.x >> 6, lane = threadIdx.x & 63;
  int a = blockIdx.x * 4 + w;        // 0..16383
  int t = a >> 1;
  int e = topk_idx[a];
  int p = 0;
  if (lane == 0) p = atomicAdd(&pos[e], 1);
  p = __shfl(p, 0);
  int slot = expOff[e] + p;
  if (lane == 0) { slot_tok[slot] = t; slot_w[slot] = topk_w[a]; }
  const float* xr = x + (size_t)t * DM;
  unsigned short* dst = Abuf + (size_t)slot * DM;
#pragma unroll
  for (int j = 0; j < 4; ++j) {
    int idx = j * 256 + lane * 4;
    float4 v = *(const float4*)(xr + idx);
    ushort4 u;
    u.x = f2bf(v.x); u.y = f2bf(v.y); u.z = f2bf(v.z); u.w = f2bf(v.w);
    *(ushort4*)(dst + idx) = u;
  }
}

// ---------- grouped GEMM: A[M][K]bf16 x Bt[e][N][K]bf16 ----------
// EPI 0: Hout = relu(acc + bias) bf16.  EPI 1: atomicAdd(accum[tok], w*(acc+bias))
template<int KDIM, int EPI>
__global__ __launch_bounds__(256) void moe_gemm(
    const unsigned short* __restrict__ A, const unsigned short* __restrict__ Bt,
    const float* __restrict__ bias, unsigned short* __restrict__ Hout,
    float* __restrict__ accum, const int* __restrict__ expOff,
    const int* __restrict__ count, const int* __restrict__ slot_tok,
    const float* __restrict__ slot_w, int N)
{
  int e = blockIdx.z;
  int off = expOff[e];
  int pad = expOff[e + 1] - off;
  int mt = blockIdx.y;
  if (mt * BM >= pad) return;
  int n0 = blockIdx.x * BN;
  int m0 = off + mt * BM;

  __shared__ __align__(16) unsigned short lsA[BM * BK];
  __shared__ __align__(16) unsigned short lsB[BN * BK];

  int lane = threadIdx.x & 63;
  int w = threadIdx.x >> 6;
  int wr = w >> 1, wc = w & 1;

  f32x4 acc[4][4] = {};

  const unsigned short* Be = Bt + (size_t)e * N * KDIM;
  int sr = lane >> 2;            // row within a 16-row staging chunk
  int sk = (lane & 3) * 8;       // k-element offset within row

  for (int kt = 0; kt < KDIM / BK; ++kt) {
    int k0 = kt * BK;
#pragma unroll
    for (int i = 0; i < 2; ++i) {
      int ch = w * 2 + i;        // 8 chunks of 16 rows, 1024B each
      gld_lds16(A + (size_t)(m0 + ch * 16 + sr) * KDIM + (k0 + sk),
                (char*)lsA + ch * 1024);
      gld_lds16(Be + (size_t)(n0 + ch * 16 + sr) * KDIM + (k0 + sk),
                (char*)lsB + ch * 1024);
    }
    __syncthreads();
    bf16x8 af[4], bfr[4];
#pragma unroll
    for (int mi = 0; mi < 4; ++mi) {
      int r = wr * 64 + mi * 16 + (lane & 15);
      af[mi] = *(const bf16x8*)((const char*)lsA + r * 64 + (lane >> 4) * 16);
    }
#pragma unroll
    for (int ni = 0; ni < 4; ++ni) {
      int r = wc * 64 + ni * 16 + (lane & 15);
      bfr[ni] = *(const bf16x8*)((const char*)lsB + r * 64 + (lane >> 4) * 16);
    }
#pragma unroll
    for (int mi = 0; mi < 4; ++mi)
#pragma unroll
      for (int ni = 0; ni < 4; ++ni)
        acc[mi][ni] = __builtin_amdgcn_mfma_f32_16x16x32_bf16(af[mi], bfr[ni], acc[mi][ni], 0, 0, 0);
    __syncthreads();
  }

  int cn = lane & 15;
  int r4 = (lane >> 4) * 4;
  if (EPI == 0) {
#pragma unroll
    for (int ni = 0; ni < 4; ++ni) {
      int col = n0 + wc * 64 + ni * 16 + cn;
      float b = bias[e * N + col];
#pragma unroll
      for (int mi = 0; mi < 4; ++mi) {
#pragma unroll
        for (int j = 0; j < 4; ++j) {
          int row = m0 + wr * 64 + mi * 16 + r4 + j;
          float v = acc[mi][ni][j] + b;
          v = v > 0.f ? v : 0.f;
          Hout[(size_t)row * N + col] = f2bf(v);
        }
      }
    }
  } else {
    int cnt = count[e];
#pragma unroll
    for (int mi = 0; mi < 4; ++mi) {
#pragma unroll
      for (int j = 0; j < 4; ++j) {
        int rloc = mt * BM + wr * 64 + mi * 16 + r4 + j;
        if (rloc < cnt) {
          int slot = off + rloc;
          int tok = slot_tok[slot];
          float wgt = slot_w[slot];
#pragma unroll
          for (int ni = 0; ni < 4; ++ni) {
            int col = n0 + wc * 64 + ni * 16 + cn;
            float v = (acc[mi][ni][j] + bias[e * N + col]) * wgt;
            atomicAdd(&accum[(size_t)tok * DM + col], v);
          }
        }
      }
    }
  }
}

// ---------- residual + LayerNorm ----------
__global__ __launch_bounds__(256) void ln_kernel(
    const float* __restrict__ x, const float* __restrict__ accum,
    const float* __restrict__ gamma, const float* __restrict__ beta,
    float* __restrict__ out)
{
  int t = blockIdx.x;
  const float* xr = x + (size_t)t * DM;
  const float* ar = accum + (size_t)t * DM;
  float z[4];
  float s = 0.f, s2 = 0.f;
#pragma unroll
  for (int i = 0; i < 4; ++i) {
    int c = threadIdx.x + i * 256;
    z[i] = xr[c] + ar[c];
    s += z[i]; s2 += z[i] * z[i];
  }
#pragma unroll
  for (int o = 1; o < 64; o <<= 1) { s += __shfl_xor(s, o); s2 += __shfl_xor(s2, o); }
  __shared__ float ls[8];
  int w = threadIdx.x >> 6, lane = threadIdx.x & 63;
  if (lane == 0) { ls[w] = s; ls[4 + w] = s2; }
  __syncthreads();
  s = ls[0] + ls[1] + ls[2] + ls[3];
  s2 = ls[4] + ls[5] + ls[6] + ls[7];
  float mu = s * (1.f / DM);
  float var = s2 * (1.f / DM) - mu * mu;
  float rstd = rsqrtf(var + 1e-5f);
  float* orow = out + (size_t)t * DM;
#pragma unroll
  for (int i = 0; i < 4; ++i) {
    int c = threadIdx.x + i * 256;
    orow[c] = (z[i] - mu) * rstd * gamma[c] + beta[c];
  }
}

// ---------- aux loss ----------
__global__ void aux_kernel(const float* __restrict__ P_sh,
                           const int* __restrict__ count, float* __restrict__ out_aux)
{
  if (threadIdx.x == 0) {
    float aux = 0.f;
    for (int e = 0; e < NE; ++e) {
      float P = 0.f;
      for (int i = 0; i < 64; ++i) P += P_sh[i * 8 + e];
      P *= (1.f / T_TOK);
      float f = count[e] * (1.f / (T_TOK * 2));
      aux += f * P;
    }
    out_aux[0] = (float)NE * aux;
  }
}

extern "C" void kernel_launch(void* const* d_in, const int* in_sizes, int n_in,
                              void* d_out, int out_size, void* d_ws, size_t ws_size,
                              hipStream_t stream)
{
  (void)in_sizes; (void)n_in; (void)out_size; (void)ws_size;
  const float* x     = (const float*)d_in[0];
  const float* Wg    = (const float*)d_in[1];
  const float* bg    = (const float*)d_in[2];
  const float* W1    = (const float*)d_in[3];
  const float* b1    = (const float*)d_in[4];
  const float* W2    = (const float*)d_in[5];
  const float* b2    = (const float*)d_in[6];
  const float* gamma = (const float*)d_in[7];
  const float* beta  = (const float*)d_in[8];
  float* out = (float*)d_out;

  char* ws = (char*)d_ws;
  size_t off = 0;
  auto alloc = [&](size_t bytes) -> void* {
    void* p = ws + off;
    off += (bytes + 255) & ~(size_t)255;
    return p;
  };
  int*   cnt_sh   = (int*)alloc(64 * 8 * 4);
  float* P_sh     = (float*)alloc(64 * 8 * 4);
  int*   count    = (int*)alloc(8 * 4);
  int*   pos      = (int*)alloc(8 * 4);
  size_t meta_end = off;                 // zero everything above each call
  int*   expOff   = (int*)alloc(9 * 4);
  int*   topk_idx = (int*)alloc(16384 * 4);
  float* topk_w   = (float*)alloc(16384 * 4);
  int*   slot_tok = (int*)alloc((size_t)SLOTS_MAX * 4);
  float* slot_w   = (float*)alloc((size_t)SLOTS_MAX * 4);
  float* accum    = (float*)alloc((size_t)T_TOK * DM * 4);
  unsigned short* W1t  = (unsigned short*)alloc((size_t)NE * DM * DFF * 2);
  unsigned short* W2t  = (unsigned short*)alloc((size_t)NE * DM * DFF * 2);
  unsigned short* Abuf = (unsigned short*)alloc((size_t)SLOTS_MAX * DM * 2);
  unsigned short* Hbuf = (unsigned short*)alloc((size_t)SLOTS_MAX * DFF * 2);

  hipMemsetAsync(d_ws, 0, meta_end, stream);
  hipMemsetAsync(accum, 0, (size_t)T_TOK * DM * 4, stream);

  transpose_convert<<<dim3(DFF / 32, DM / 32, NE), 256, 0, stream>>>(W1, W1t, DM, DFF);
  transpose_convert<<<dim3(DM / 32, DFF / 32, NE), 256, 0, stream>>>(W2, W2t, DFF, DM);
  router_kernel<<<512, 256, 0, stream>>>(x, Wg, bg, topk_idx, topk_w, cnt_sh, P_sh);
  offsets_kernel<<<1, 64, 0, stream>>>(cnt_sh, count, expOff);
  gather_kernel<<<4096, 256, 0, stream>>>(x, topk_idx, topk_w, expOff, pos, slot_tok, slot_w, Abuf);
  moe_gemm<DM, 0><<<dim3(DFF / BN, 64, NE), 256, 0, stream>>>(
      Abuf, W1t, b1, Hbuf, nullptr, expOff, count, slot_tok, slot_w, DFF);
  moe_gemm<DFF, 1><<<dim3(DM / BN, 64, NE), 256, 0, stream>>>(
      Hbuf, W2t, b2, nullptr, accum, expOff, count, slot_tok, slot_w, DM);
  ln_kernel<<<T_TOK, 256, 0, stream>>>(x, accum, gamma, beta, out);
  aux_kernel<<<1, 64, 0, stream>>>(P_sh, count, out + (size_t)T_TOK * DM);
}